// Round 11
// baseline (10895.915 us; speedup 1.0000x reference)
//
#include <hip/hip_runtime.h>

#define B_ 512
#define T_ 256
#define D_ 128
#define H_ 512

typedef _Float16 f16x8 __attribute__((ext_vector_type(8)));
typedef float f32x4 __attribute__((ext_vector_type(4)));
typedef unsigned long long u64;

__device__ __forceinline__ float sigm(float x) { return 1.f / (1.f + __expf(-x)); }
__device__ __forceinline__ float tanh_(float x) { return 2.f / (1.f + __expf(-2.f * x)) - 1.f; }

// ---------------- weight convert: fp32 -> fp16, transposed to [N][K] ----------------
__global__ void k_convert(const float* __restrict__ k0, const float* __restrict__ r0,
                          const float* __restrict__ k1, const float* __restrict__ r1,
                          const float* __restrict__ W,
                          _Float16* __restrict__ wB0T,  // [2048][640]
                          _Float16* __restrict__ wB1T,  // [2048][1024]
                          _Float16* __restrict__ wWT)   // [128][512]
{
    int tid = blockIdx.x * blockDim.x + threadIdx.x;
    int nth = gridDim.x * blockDim.x;
    for (int idx = tid; idx < 640 * 2048; idx += nth) {
        int k = idx >> 11, n = idx & 2047;
        float v = (k < 128) ? k0[k * 2048 + n] : r0[(k - 128) * 2048 + n];
        wB0T[n * 640 + k] = (_Float16)v;
    }
    for (int idx = tid; idx < 1024 * 2048; idx += nth) {
        int k = idx >> 11, n = idx & 2047;
        float v = (k < 512) ? k1[k * 2048 + n] : r1[(k - 512) * 2048 + n];
        wB1T[n * 1024 + k] = (_Float16)v;
    }
    for (int idx = tid; idx < 512 * 128; idx += nth) {
        int k = idx >> 7, n = idx & 127;
        wWT[n * 512 + k] = (_Float16)W[k * 128 + n];
    }
}

// ---------------- init: cur = x[:,0,:] fp16, zero h/c state ----------------
__global__ void k_init(const float* __restrict__ x, _Float16* __restrict__ cur,
                       _Float16* __restrict__ h0a, _Float16* __restrict__ h0b,
                       _Float16* __restrict__ h1a, _Float16* __restrict__ h1b,
                       float* __restrict__ c0, float* __restrict__ c1)
{
    int tid = blockIdx.x * blockDim.x + threadIdx.x;
    int nth = gridDim.x * blockDim.x;
    for (int idx = tid; idx < B_ * D_; idx += nth) {
        int b = idx >> 7, d = idx & 127;
        cur[idx] = (_Float16)x[b * (T_ * D_) + d];   // t=0: 128.0 exact in fp16
    }
    for (int idx = tid; idx < B_ * H_; idx += nth) {
        h0a[idx] = (_Float16)0.f; h0b[idx] = (_Float16)0.f;
        h1a[idx] = (_Float16)0.f; h1b[idx] = (_Float16)0.f;
        c0[idx] = 0.f; c1[idx] = 0.f;
    }
}

// ---------------- one LSTM layer step, fp16 GEMM, BK=128, swizzled LDS, depth-2 prefetch ----
// z^T fragments via swapped-operand MFMA: lane owns row m0+wpair*16+(lane&15),
// 4 consecutive cols j0+(lane>>4)*4..+3. A=[A1|A2] K-segments; BT [2048][KTOT].
// 8 waves: wpair=wave>>1 (16-row group), ksub=wave&1 (K-half of the 128 tile).
// Depth-2 register prefetch: loads for tile i+2 issue as tile i is written to LDS,
// giving ~2 full iterations of issue-to-use distance to cover post-boundary L2 latency.
template <int KTOT, int K1>
__global__ __launch_bounds__(512) void k_layer(
    const _Float16* __restrict__ A1, int lda1,
    const _Float16* __restrict__ A2, int lda2,
    const _Float16* __restrict__ BT,
    const float* __restrict__ bias,       // [2048] gate order i,f,g,o
    float* __restrict__ cst,              // [512][512] fp32 rmw
    _Float16* __restrict__ hout,
    float* __restrict__ hout_f32)         // optional fp32 copy (last_cell)
{
    constexpr int LSTR = 144;
    constexpr int NIT = KTOT / 128;
    __shared__ __align__(16) char smem[2 * 64 * LSTR * 2];   // 36864 B
    _Float16* sA = (_Float16*)smem;
    _Float16* sB = sA + 64 * LSTR;
    float* szred = (float*)smem;          // aliased after main loop (barrier-separated)

    const int j0 = blockIdx.x * 16;
    const int m0 = blockIdx.y * 64;
    const int tid = threadIdx.x;
    const int lane = tid & 63;
    const int wave = tid >> 6;
    const int wpair = wave >> 1;
    const int ksub = wave & 1;

    // staging: thread -> (row, 16-elem k chunk)
    const int srow = tid >> 3;
    const int skc = (tid & 7) << 4;       // 0,16,...,112
    const int swz = (srow & 7) << 3;
    const int sw1 = srow * LSTR + (skc ^ swz);
    const int sw2 = srow * LSTR + ((skc + 8) ^ swz);
    const int bgrow = (srow >> 4) * 512 + j0 + (srow & 15);

    uint4 rA0[2], rA1[2], rB0[2], rB1[2];
    auto loadA = [&](int kb, int s) {
        int k = kb + skc;
        const _Float16* a; size_t off;
        if (k < K1) { a = A1; off = (size_t)(m0 + srow) * lda1 + k; }
        else        { a = A2; off = (size_t)(m0 + srow) * lda2 + (k - K1); }
        rA0[s] = *reinterpret_cast<const uint4*>(a + off);
        rA1[s] = *reinterpret_cast<const uint4*>(a + off + 8);
    };
    auto loadB = [&](int kb, int s) {
        size_t off = (size_t)bgrow * KTOT + kb + skc;
        rB0[s] = *reinterpret_cast<const uint4*>(BT + off);
        rB1[s] = *reinterpret_cast<const uint4*>(BT + off + 8);
    };

    loadA(0, 0); loadB(0, 0);
    loadA(128, 1); loadB(128, 1);         // KTOT >= 256 always (640 / 1024)

    f32x4 acc[4] = {};
    const int arow = wpair * 16 + (lane & 15);
    const int abase = arow * LSTR;
    const int aswz = (arow & 7) << 3;
    const int kfrag = ksub * 64 + ((lane >> 4) << 3);

#pragma unroll
    for (int i = 0; i < NIT; ++i) {
        const int s = i & 1;              // static under full unroll
        __syncthreads();
        *reinterpret_cast<uint4*>(&sA[sw1]) = rA0[s];
        *reinterpret_cast<uint4*>(&sA[sw2]) = rA1[s];
        *reinterpret_cast<uint4*>(&sB[sw1]) = rB0[s];
        *reinterpret_cast<uint4*>(&sB[sw2]) = rB1[s];
        if (i + 2 < NIT) { loadA((i + 2) * 128, s); loadB((i + 2) * 128, s); }
        __syncthreads();
#pragma unroll
        for (int kk = 0; kk < 2; ++kk) {
            int ko = kfrag + kk * 32;
            f16x8 a = *reinterpret_cast<const f16x8*>(&sA[abase + (ko ^ aswz)]);
#pragma unroll
            for (int g = 0; g < 4; ++g) {
                int br = g * 16 + (lane & 15);
                f16x8 b = *reinterpret_cast<const f16x8*>(&sB[br * LSTR + (ko ^ ((br & 7) << 3))]);
                acc[g] = __builtin_amdgcn_mfma_f32_16x16x32_f16(b, a, acc[g], 0, 0, 0);
            }
        }
    }

    __syncthreads();                      // staging reads done; szred may alias
    if (ksub == 1) {
        float* zr = &szred[(wpair * 64 + lane) * 21];
#pragma unroll
        for (int g = 0; g < 4; ++g)
#pragma unroll
            for (int r = 0; r < 4; ++r)
                zr[g * 4 + r] = acc[g][r];
    }
    __syncthreads();
    if (ksub == 0) {
        const int row  = m0 + wpair * 16 + (lane & 15);
        const int colb = j0 + ((lane >> 4) << 2);
        const float* zr = &szred[(wpair * 64 + lane) * 21];
        f32x4 bi4 = *reinterpret_cast<const f32x4*>(&bias[colb]);
        f32x4 bf4 = *reinterpret_cast<const f32x4*>(&bias[512 + colb]);
        f32x4 bg4 = *reinterpret_cast<const f32x4*>(&bias[1024 + colb]);
        f32x4 bo4 = *reinterpret_cast<const f32x4*>(&bias[1536 + colb]);
        f32x4 c4 = *reinterpret_cast<f32x4*>(&cst[row * H_ + colb]);
        union { _Float16 h[4]; u64 u; } hh;
        f32x4 h4;
#pragma unroll
        for (int r = 0; r < 4; ++r) {
            float zi = acc[0][r] + zr[0 + r] + bi4[r];
            float zf = acc[1][r] + zr[4 + r] + bf4[r];
            float zg = acc[2][r] + zr[8 + r] + bg4[r];
            float zo = acc[3][r] + zr[12 + r] + bo4[r];
            float gi = sigm(zi), gf = sigm(zf), gg = tanh_(zg), go = sigm(zo);
            float c = gf * c4[r] + gi * gg;
            c4[r] = c;
            float h = go * tanh_(c);
            h4[r] = h;
            hh.h[r] = (_Float16)h;
        }
        *reinterpret_cast<f32x4*>(&cst[row * H_ + colb]) = c4;
        *reinterpret_cast<u64*>(&hout[row * H_ + colb]) = hh.u;
        if (hout_f32) *reinterpret_cast<f32x4*>(&hout_f32[row * H_ + colb]) = h4;
    }
}

// ---------------- pred: one 16x16 tile/WG, 8-wave K-split, direct frag loads ----------------
// Grid 256 WGs (32 b-row tiles x 8 d-col tiles), 512 threads.
__global__ __launch_bounds__(512) void k_pred(
    const _Float16* __restrict__ h1prev, // [512][512]
    const _Float16* __restrict__ WT,     // [128][512]
    const float* __restrict__ bout,
    const float* __restrict__ x,         // [512][256][128]
    int t,
    _Float16* __restrict__ cur,          // [512][128]
    float* __restrict__ outPred)         // [B*(T-1)][128] region of d_out
{
    __shared__ float sred[512 * 5];

    const int tid = threadIdx.x;
    const int wave = tid >> 6, l = tid & 63;
    const int pr = blockIdx.x >> 3;       // b-row tile 0..31
    const int pc = blockIdx.x & 7;        // d-col tile 0..7
    const int arow = (pr * 16 + (l & 15)) * 512;
    const int brow = (pc * 16 + (l & 15)) * 512;
    const int kof = (l >> 4) << 3;

    f32x4 acc = {};
#pragma unroll
    for (int kk = 0; kk < 2; ++kk) {
        int k = wave * 64 + kk * 32 + kof;
        f16x8 a = *reinterpret_cast<const f16x8*>(h1prev + arow + k);
        f16x8 b = *reinterpret_cast<const f16x8*>(WT + brow + k);
        // swapped: lane holds b=pr*16+(l&15), d=pc*16+(l>>4)*4+r
        acc = __builtin_amdgcn_mfma_f32_16x16x32_f16(b, a, acc, 0, 0, 0);
    }
    {
        float* sr = &sred[(wave * 64 + l) * 5];
#pragma unroll
        for (int r = 0; r < 4; ++r) sr[r] = acc[r];
    }
    __syncthreads();
    if (wave == 0) {
#pragma unroll
        for (int w = 1; w < 8; ++w) {
            const float* sr = &sred[(w * 64 + l) * 5];
#pragma unroll
            for (int r = 0; r < 4; ++r) acc[r] += sr[r];
        }
        const int b = pr * 16 + (l & 15);
        const int colb = pc * 16 + ((l >> 4) << 2);
        f32x4 bo4 = *reinterpret_cast<const f32x4*>(&bout[colb]);
        f32x4 xv4 = *reinterpret_cast<const f32x4*>(&x[((size_t)b * T_ + t) * D_ + colb]);
        f32x4 p4;
        union { _Float16 h[4]; u64 u; } ch;
#pragma unroll
        for (int r = 0; r < 4; ++r) {
            float pred = acc[r] + bo4[r];
            p4[r] = pred;
            float cv = (xv4[r] == 128.0f) ? pred : xv4[r];
            ch.h[r] = (_Float16)cv;
        }
        *reinterpret_cast<f32x4*>(&outPred[((size_t)b * (T_ - 1) + (t - 1)) * D_ + colb]) = p4;
        *reinterpret_cast<u64*>(&cur[b * D_ + colb]) = ch.u;
    }
}

extern "C" void kernel_launch(void* const* d_in, const int* in_sizes, int n_in,
                              void* d_out, int out_size, void* d_ws, size_t ws_size,
                              hipStream_t stream)
{
    const float* x  = (const float*)d_in[0];
    const float* k0 = (const float*)d_in[1];
    const float* r0 = (const float*)d_in[2];
    const float* b0 = (const float*)d_in[3];
    const float* k1 = (const float*)d_in[4];
    const float* r1 = (const float*)d_in[5];
    const float* b1 = (const float*)d_in[6];
    const float* W  = (const float*)d_in[7];
    const float* bo = (const float*)d_in[8];
    float* out = (float*)d_out;

    char* ws = (char*)d_ws;
    size_t off = 0;
    auto alloc = [&](size_t bytes) { void* p = ws + off; off += (bytes + 255) & ~255ull; return p; };
    _Float16* wB0T = (_Float16*)alloc((size_t)2048 * 640 * 2);
    _Float16* wB1T = (_Float16*)alloc((size_t)2048 * 1024 * 2);
    _Float16* wWT  = (_Float16*)alloc((size_t)128 * 512 * 2);
    _Float16* cur  = (_Float16*)alloc((size_t)B_ * D_ * 2);
    _Float16* h0[2] = { (_Float16*)alloc((size_t)B_ * H_ * 2), (_Float16*)alloc((size_t)B_ * H_ * 2) };
    _Float16* h1[2] = { (_Float16*)alloc((size_t)B_ * H_ * 2), (_Float16*)alloc((size_t)B_ * H_ * 2) };
    float* c0 = (float*)alloc((size_t)B_ * H_ * 4);
    float* c1 = (float*)alloc((size_t)B_ * H_ * 4);

    k_convert<<<2048, 256, 0, stream>>>(k0, r0, k1, r1, W, wB0T, wB1T, wWT);
    k_init<<<1024, 256, 0, stream>>>(x, cur, h0[0], h0[1], h1[0], h1[1], c0, c1);

    float* lastcell = out + (size_t)B_ * (T_ - 1) * D_;

    for (int t = 0; t < T_; ++t) {
        int cu = t & 1, pv = cu ^ 1;
        if (t > 0)
            k_pred<<<256, 512, 0, stream>>>(h1[pv], wWT, bo, x, t, cur, out);
        k_layer<640, 128><<<dim3(32, 8), 512, 0, stream>>>(
            cur, D_, h0[pv], H_, wB0T, b0, c0, h0[cu], nullptr);
        k_layer<1024, 512><<<dim3(32, 8), 512, 0, stream>>>(
            h0[cu], H_, h1[pv], H_, wB1T, b1, c1, h1[cu],
            (t == T_ - 1) ? lastcell : nullptr);
    }
}

// Round 12
// 5385.404 us; speedup vs baseline: 2.0232x; 2.0232x over previous
//
#include <hip/hip_runtime.h>

#define B_ 512
#define T_ 256
#define D_ 128
#define H_ 512

typedef _Float16 f16x8 __attribute__((ext_vector_type(8)));
typedef float f32x4 __attribute__((ext_vector_type(4)));
typedef unsigned long long u64;

__device__ __forceinline__ float sigm(float x) { return 1.f / (1.f + __expf(-x)); }
__device__ __forceinline__ float tanh_(float x) { return 2.f / (1.f + __expf(-2.f * x)) - 1.f; }

// ---------------- weight convert: fp32 -> fp16, transposed to [N][K] ----------------
__global__ void k_convert(const float* __restrict__ k0, const float* __restrict__ r0,
                          const float* __restrict__ k1, const float* __restrict__ r1,
                          const float* __restrict__ W,
                          _Float16* __restrict__ wB0T,  // [2048][640]
                          _Float16* __restrict__ wB1T,  // [2048][1024]
                          _Float16* __restrict__ wWT)   // [128][512]
{
    int tid = blockIdx.x * blockDim.x + threadIdx.x;
    int nth = gridDim.x * blockDim.x;
    for (int idx = tid; idx < 640 * 2048; idx += nth) {
        int k = idx >> 11, n = idx & 2047;
        float v = (k < 128) ? k0[k * 2048 + n] : r0[(k - 128) * 2048 + n];
        wB0T[n * 640 + k] = (_Float16)v;
    }
    for (int idx = tid; idx < 1024 * 2048; idx += nth) {
        int k = idx >> 11, n = idx & 2047;
        float v = (k < 512) ? k1[k * 2048 + n] : r1[(k - 512) * 2048 + n];
        wB1T[n * 1024 + k] = (_Float16)v;
    }
    for (int idx = tid; idx < 512 * 128; idx += nth) {
        int k = idx >> 7, n = idx & 127;
        wWT[n * 512 + k] = (_Float16)W[k * 128 + n];
    }
}

// ---------------- init: cur = x[:,0,:] fp16, zero h/c state ----------------
__global__ void k_init(const float* __restrict__ x, _Float16* __restrict__ cur,
                       _Float16* __restrict__ h0a, _Float16* __restrict__ h0b,
                       _Float16* __restrict__ h1a, _Float16* __restrict__ h1b,
                       float* __restrict__ c0, float* __restrict__ c1)
{
    int tid = blockIdx.x * blockDim.x + threadIdx.x;
    int nth = gridDim.x * blockDim.x;
    for (int idx = tid; idx < B_ * D_; idx += nth) {
        int b = idx >> 7, d = idx & 127;
        cur[idx] = (_Float16)x[b * (T_ * D_) + d];   // t=0: 128.0 exact in fp16
    }
    for (int idx = tid; idx < B_ * H_; idx += nth) {
        h0a[idx] = (_Float16)0.f; h0b[idx] = (_Float16)0.f;
        h1a[idx] = (_Float16)0.f; h1b[idx] = (_Float16)0.f;
        c0[idx] = 0.f; c1[idx] = 0.f;
    }
}

// ---------------- one LSTM layer step, fp16 GEMM, BK=128, swizzled LDS ----------------
// 32-row m-tiles, 256 threads (4 waves) -> 2 WGs/CU for cross-block latency overlap.
// z^T fragments via swapped-operand MFMA: lane owns row m0+wpair*16+(lane&15),
// 4 consecutive cols j0+(lane>>4)*4..+3. A=[A1|A2] K-segments; BT [2048][KTOT].
// waves: wpair=wave>>1 (16-row group), ksub=wave&1 (64-K half of the 128 tile).
// Depth-1 register prefetch, dynamic loop (r9-proven; do NOT unrol the K-loop).
template <int KTOT, int K1>
__global__ __launch_bounds__(256) void k_layer(
    const _Float16* __restrict__ A1, int lda1,
    const _Float16* __restrict__ A2, int lda2,
    const _Float16* __restrict__ BT,
    const float* __restrict__ bias,       // [2048] gate order i,f,g,o
    float* __restrict__ cst,              // [512][512] fp32 rmw
    _Float16* __restrict__ hout,
    float* __restrict__ hout_f32)         // optional fp32 copy (last_cell)
{
    constexpr int LSTR = 144;
    __shared__ __align__(16) char smem[(32 + 64) * LSTR * 2];   // 27648 B -> 2 WGs/CU
    _Float16* sA = (_Float16*)smem;                             // [32][144]
    _Float16* sB = sA + 32 * LSTR;                              // [64][144]
    float* szred = (float*)smem;          // aliased after main loop (barrier-separated)

    const int j0 = blockIdx.x * 16;
    const int m0 = blockIdx.y * 32;
    const int tid = threadIdx.x;
    const int lane = tid & 63;
    const int wave = tid >> 6;
    const int wpair = wave >> 1;
    const int ksub = wave & 1;

    // A staging: 32 rows x 128 k, thread -> (row, 16-elem chunk)
    const int sArow = tid >> 3;
    const int sAkc = (tid & 7) << 4;
    const int swzA = (sArow & 7) << 3;
    const int swA1 = sArow * LSTR + (sAkc ^ swzA);
    const int swA2 = sArow * LSTR + ((sAkc + 8) ^ swzA);
    // B staging: 64 rows x 128 k, thread -> (row, 32-elem chunk)
    const int sBrow = tid >> 2;
    const int sBkc = (tid & 3) << 5;
    const int swzB = (sBrow & 7) << 3;
    const int swB1 = sBrow * LSTR + ((sBkc + 0) ^ swzB);
    const int swB2 = sBrow * LSTR + ((sBkc + 8) ^ swzB);
    const int swB3 = sBrow * LSTR + ((sBkc + 16) ^ swzB);
    const int swB4 = sBrow * LSTR + ((sBkc + 24) ^ swzB);
    const int bgrow = (sBrow >> 4) * 512 + j0 + (sBrow & 15);

    uint4 rA0, rA1, rB0, rB1, rB2, rB3;
    auto loadA = [&](int kb) {
        int k = kb + sAkc;
        const _Float16* a; size_t off;
        if (k < K1) { a = A1; off = (size_t)(m0 + sArow) * lda1 + k; }
        else        { a = A2; off = (size_t)(m0 + sArow) * lda2 + (k - K1); }
        rA0 = *reinterpret_cast<const uint4*>(a + off);
        rA1 = *reinterpret_cast<const uint4*>(a + off + 8);
    };
    auto loadB = [&](int kb) {
        size_t off = (size_t)bgrow * KTOT + kb + sBkc;
        rB0 = *reinterpret_cast<const uint4*>(BT + off);
        rB1 = *reinterpret_cast<const uint4*>(BT + off + 8);
        rB2 = *reinterpret_cast<const uint4*>(BT + off + 16);
        rB3 = *reinterpret_cast<const uint4*>(BT + off + 24);
    };

    loadA(0); loadB(0);

    f32x4 acc[4] = {};
    const int arow = wpair * 16 + (lane & 15);
    const int abase = arow * LSTR;
    const int aswz = (arow & 7) << 3;
    const int kfrag = ksub * 64 + ((lane >> 4) << 3);

    for (int kb = 0; kb < KTOT; kb += 128) {
        __syncthreads();
        *reinterpret_cast<uint4*>(&sA[swA1]) = rA0;
        *reinterpret_cast<uint4*>(&sA[swA2]) = rA1;
        *reinterpret_cast<uint4*>(&sB[swB1]) = rB0;
        *reinterpret_cast<uint4*>(&sB[swB2]) = rB1;
        *reinterpret_cast<uint4*>(&sB[swB3]) = rB2;
        *reinterpret_cast<uint4*>(&sB[swB4]) = rB3;
        if (kb + 128 < KTOT) { loadA(kb + 128); loadB(kb + 128); }
        __syncthreads();
#pragma unroll
        for (int kk = 0; kk < 2; ++kk) {
            int ko = kfrag + kk * 32;
            f16x8 a = *reinterpret_cast<const f16x8*>(&sA[abase + (ko ^ aswz)]);
#pragma unroll
            for (int g = 0; g < 4; ++g) {
                int br = g * 16 + (lane & 15);
                f16x8 b = *reinterpret_cast<const f16x8*>(&sB[br * LSTR + (ko ^ ((br & 7) << 3))]);
                acc[g] = __builtin_amdgcn_mfma_f32_16x16x32_f16(b, a, acc[g], 0, 0, 0);
            }
        }
    }

    __syncthreads();                      // staging reads done; szred may alias
    if (ksub == 1) {
        float* zr = &szred[(wpair * 64 + lane) * 21];
#pragma unroll
        for (int g = 0; g < 4; ++g)
#pragma unroll
            for (int r = 0; r < 4; ++r)
                zr[g * 4 + r] = acc[g][r];
    }
    __syncthreads();
    if (ksub == 0) {
        const int row  = m0 + wpair * 16 + (lane & 15);
        const int colb = j0 + ((lane >> 4) << 2);
        const float* zr = &szred[(wpair * 64 + lane) * 21];
        f32x4 bi4 = *reinterpret_cast<const f32x4*>(&bias[colb]);
        f32x4 bf4 = *reinterpret_cast<const f32x4*>(&bias[512 + colb]);
        f32x4 bg4 = *reinterpret_cast<const f32x4*>(&bias[1024 + colb]);
        f32x4 bo4 = *reinterpret_cast<const f32x4*>(&bias[1536 + colb]);
        f32x4 c4 = *reinterpret_cast<f32x4*>(&cst[row * H_ + colb]);
        union { _Float16 h[4]; u64 u; } hh;
        f32x4 h4;
#pragma unroll
        for (int r = 0; r < 4; ++r) {
            float zi = acc[0][r] + zr[0 + r] + bi4[r];
            float zf = acc[1][r] + zr[4 + r] + bf4[r];
            float zg = acc[2][r] + zr[8 + r] + bg4[r];
            float zo = acc[3][r] + zr[12 + r] + bo4[r];
            float gi = sigm(zi), gf = sigm(zf), gg = tanh_(zg), go = sigm(zo);
            float c = gf * c4[r] + gi * gg;
            c4[r] = c;
            float h = go * tanh_(c);
            h4[r] = h;
            hh.h[r] = (_Float16)h;
        }
        *reinterpret_cast<f32x4*>(&cst[row * H_ + colb]) = c4;
        *reinterpret_cast<u64*>(&hout[row * H_ + colb]) = hh.u;
        if (hout_f32) *reinterpret_cast<f32x4*>(&hout_f32[row * H_ + colb]) = h4;
    }
}

// ---------------- pred: one 16x16 tile/WG, 8-wave K-split, direct frag loads ----------------
// Grid 256 WGs (32 b-row tiles x 8 d-col tiles), 512 threads.  (r9 verbatim)
__global__ __launch_bounds__(512) void k_pred(
    const _Float16* __restrict__ h1prev, // [512][512]
    const _Float16* __restrict__ WT,     // [128][512]
    const float* __restrict__ bout,
    const float* __restrict__ x,         // [512][256][128]
    int t,
    _Float16* __restrict__ cur,          // [512][128]
    float* __restrict__ outPred)         // [B*(T-1)][128] region of d_out
{
    __shared__ float sred[512 * 5];

    const int tid = threadIdx.x;
    const int wave = tid >> 6, l = tid & 63;
    const int pr = blockIdx.x >> 3;       // b-row tile 0..31
    const int pc = blockIdx.x & 7;        // d-col tile 0..7
    const int arow = (pr * 16 + (l & 15)) * 512;
    const int brow = (pc * 16 + (l & 15)) * 512;
    const int kof = (l >> 4) << 3;

    f32x4 acc = {};
#pragma unroll
    for (int kk = 0; kk < 2; ++kk) {
        int k = wave * 64 + kk * 32 + kof;
        f16x8 a = *reinterpret_cast<const f16x8*>(h1prev + arow + k);
        f16x8 b = *reinterpret_cast<const f16x8*>(WT + brow + k);
        // swapped: lane holds b=pr*16+(l&15), d=pc*16+(l>>4)*4+r
        acc = __builtin_amdgcn_mfma_f32_16x16x32_f16(b, a, acc, 0, 0, 0);
    }
    {
        float* sr = &sred[(wave * 64 + l) * 5];
#pragma unroll
        for (int r = 0; r < 4; ++r) sr[r] = acc[r];
    }
    __syncthreads();
    if (wave == 0) {
#pragma unroll
        for (int w = 1; w < 8; ++w) {
            const float* sr = &sred[(w * 64 + l) * 5];
#pragma unroll
            for (int r = 0; r < 4; ++r) acc[r] += sr[r];
        }
        const int b = pr * 16 + (l & 15);
        const int colb = pc * 16 + ((l >> 4) << 2);
        f32x4 bo4 = *reinterpret_cast<const f32x4*>(&bout[colb]);
        f32x4 xv4 = *reinterpret_cast<const f32x4*>(&x[((size_t)b * T_ + t) * D_ + colb]);
        f32x4 p4;
        union { _Float16 h[4]; u64 u; } ch;
#pragma unroll
        for (int r = 0; r < 4; ++r) {
            float pred = acc[r] + bo4[r];
            p4[r] = pred;
            float cv = (xv4[r] == 128.0f) ? pred : xv4[r];
            ch.h[r] = (_Float16)cv;
        }
        *reinterpret_cast<f32x4*>(&outPred[((size_t)b * (T_ - 1) + (t - 1)) * D_ + colb]) = p4;
        *reinterpret_cast<u64*>(&cur[b * D_ + colb]) = ch.u;
    }
}

extern "C" void kernel_launch(void* const* d_in, const int* in_sizes, int n_in,
                              void* d_out, int out_size, void* d_ws, size_t ws_size,
                              hipStream_t stream)
{
    const float* x  = (const float*)d_in[0];
    const float* k0 = (const float*)d_in[1];
    const float* r0 = (const float*)d_in[2];
    const float* b0 = (const float*)d_in[3];
    const float* k1 = (const float*)d_in[4];
    const float* r1 = (const float*)d_in[5];
    const float* b1 = (const float*)d_in[6];
    const float* W  = (const float*)d_in[7];
    const float* bo = (const float*)d_in[8];
    float* out = (float*)d_out;

    char* ws = (char*)d_ws;
    size_t off = 0;
    auto alloc = [&](size_t bytes) { void* p = ws + off; off += (bytes + 255) & ~255ull; return p; };
    _Float16* wB0T = (_Float16*)alloc((size_t)2048 * 640 * 2);
    _Float16* wB1T = (_Float16*)alloc((size_t)2048 * 1024 * 2);
    _Float16* wWT  = (_Float16*)alloc((size_t)128 * 512 * 2);
    _Float16* cur  = (_Float16*)alloc((size_t)B_ * D_ * 2);
    _Float16* h0[2] = { (_Float16*)alloc((size_t)B_ * H_ * 2), (_Float16*)alloc((size_t)B_ * H_ * 2) };
    _Float16* h1[2] = { (_Float16*)alloc((size_t)B_ * H_ * 2), (_Float16*)alloc((size_t)B_ * H_ * 2) };
    float* c0 = (float*)alloc((size_t)B_ * H_ * 4);
    float* c1 = (float*)alloc((size_t)B_ * H_ * 4);

    k_convert<<<2048, 256, 0, stream>>>(k0, r0, k1, r1, W, wB0T, wB1T, wWT);
    k_init<<<1024, 256, 0, stream>>>(x, cur, h0[0], h0[1], h1[0], h1[1], c0, c1);

    float* lastcell = out + (size_t)B_ * (T_ - 1) * D_;

    for (int t = 0; t < T_; ++t) {
        int cu = t & 1, pv = cu ^ 1;
        if (t > 0)
            k_pred<<<256, 512, 0, stream>>>(h1[pv], wWT, bo, x, t, cur, out);
        k_layer<640, 128><<<dim3(32, 16), 256, 0, stream>>>(
            cur, D_, h0[pv], H_, wB0T, b0, c0, h0[cu], nullptr);
        k_layer<1024, 512><<<dim3(32, 16), 256, 0, stream>>>(
            h0[cu], H_, h1[pv], H_, wB1T, b1, c1, h1[cu],
            (t == T_ - 1) ? lastcell : nullptr);
    }
}

// Round 13
// 5185.063 us; speedup vs baseline: 2.1014x; 1.0386x over previous
//
#include <hip/hip_runtime.h>

#define B_ 512
#define T_ 256
#define D_ 128
#define H_ 512

typedef _Float16 f16x8 __attribute__((ext_vector_type(8)));
typedef float f32x4 __attribute__((ext_vector_type(4)));
typedef unsigned long long u64;

__device__ __forceinline__ float sigm(float x) { return 1.f / (1.f + __expf(-x)); }
__device__ __forceinline__ float tanh_(float x) { return 2.f / (1.f + __expf(-2.f * x)) - 1.f; }

// ---------------- weight convert: fp32 -> fp16, transposed to [N][K] ----------------
__global__ void k_convert(const float* __restrict__ k0, const float* __restrict__ r0,
                          const float* __restrict__ k1, const float* __restrict__ r1,
                          const float* __restrict__ W,
                          _Float16* __restrict__ wB0T,  // [2048][640]
                          _Float16* __restrict__ wB1T,  // [2048][1024]
                          _Float16* __restrict__ wWT)   // [128][512]
{
    int tid = blockIdx.x * blockDim.x + threadIdx.x;
    int nth = gridDim.x * blockDim.x;
    for (int idx = tid; idx < 640 * 2048; idx += nth) {
        int k = idx >> 11, n = idx & 2047;
        float v = (k < 128) ? k0[k * 2048 + n] : r0[(k - 128) * 2048 + n];
        wB0T[n * 640 + k] = (_Float16)v;
    }
    for (int idx = tid; idx < 1024 * 2048; idx += nth) {
        int k = idx >> 11, n = idx & 2047;
        float v = (k < 512) ? k1[k * 2048 + n] : r1[(k - 512) * 2048 + n];
        wB1T[n * 1024 + k] = (_Float16)v;
    }
    for (int idx = tid; idx < 512 * 128; idx += nth) {
        int k = idx >> 7, n = idx & 127;
        wWT[n * 512 + k] = (_Float16)W[k * 128 + n];
    }
}

// ---------------- init: cur = x[:,0,:] fp16, zero h/c state ----------------
__global__ void k_init(const float* __restrict__ x, _Float16* __restrict__ cur,
                       _Float16* __restrict__ h0a, _Float16* __restrict__ h0b,
                       _Float16* __restrict__ h1a, _Float16* __restrict__ h1b,
                       float* __restrict__ c0, float* __restrict__ c1)
{
    int tid = blockIdx.x * blockDim.x + threadIdx.x;
    int nth = gridDim.x * blockDim.x;
    for (int idx = tid; idx < B_ * D_; idx += nth) {
        int b = idx >> 7, d = idx & 127;
        cur[idx] = (_Float16)x[b * (T_ * D_) + d];   // t=0: 128.0 exact in fp16
    }
    for (int idx = tid; idx < B_ * H_; idx += nth) {
        h0a[idx] = (_Float16)0.f; h0b[idx] = (_Float16)0.f;
        h1a[idx] = (_Float16)0.f; h1b[idx] = (_Float16)0.f;
        c0[idx] = 0.f; c1[idx] = 0.f;
    }
}

// ---------------- one LSTM layer step, fp16 GEMM, BK=128, swizzled double-buffered LDS ----
// z^T fragments via swapped-operand MFMA: lane owns row m0+wpair*16+(lane&15),
// 4 consecutive cols j0+(lane>>4)*4..+3. A=[A1|A2] K-segments; BT [2048][KTOT].
// 8 waves: wpair=wave>>1 (16-row group), ksub=wave&1 (K-half of the 128 tile).
// Double-buffered LDS -> ONE __syncthreads per K-iter (end-of-iter barrier orders
// reads of stage[(i-1)&1] before iter-i writes to stage[(i+1)&1], the same buffer).
// Dynamic loop, dynamic LDS *pointers* (no register-array indexing), single reg set.
template <int KTOT, int K1>
__global__ __launch_bounds__(512) void k_layer(
    const _Float16* __restrict__ A1, int lda1,
    const _Float16* __restrict__ A2, int lda2,
    const _Float16* __restrict__ BT,
    const float* __restrict__ bias,       // [2048] gate order i,f,g,o
    float* __restrict__ cst,              // [512][512] fp32 rmw
    _Float16* __restrict__ hout,
    float* __restrict__ hout_f32)         // optional fp32 copy (last_cell)
{
    constexpr int LSTR = 144;
    constexpr int NIT = KTOT / 128;
    constexpr int STG = 2 * 64 * LSTR;    // elems per stage (A tile + B tile)
    __shared__ __align__(16) char smem[2 * STG * 2];   // 73728 B, 2 stages
    _Float16* s0 = (_Float16*)smem;
    float* szred = (float*)smem;          // aliased after main loop (barrier-separated)

    const int j0 = blockIdx.x * 16;
    const int m0 = blockIdx.y * 64;
    const int tid = threadIdx.x;
    const int lane = tid & 63;
    const int wave = tid >> 6;
    const int wpair = wave >> 1;
    const int ksub = wave & 1;

    // staging: thread -> (row, 16-elem k chunk)
    const int srow = tid >> 3;
    const int skc = (tid & 7) << 4;       // 0,16,...,112
    const int swz = (srow & 7) << 3;
    const int sw1 = srow * LSTR + (skc ^ swz);
    const int sw2 = srow * LSTR + ((skc + 8) ^ swz);
    const int bgrow = (srow >> 4) * 512 + j0 + (srow & 15);

    uint4 rA0, rA1, rB0, rB1;
    auto loadA = [&](int kb) {
        int k = kb + skc;
        const _Float16* a; size_t off;
        if (k < K1) { a = A1; off = (size_t)(m0 + srow) * lda1 + k; }
        else        { a = A2; off = (size_t)(m0 + srow) * lda2 + (k - K1); }
        rA0 = *reinterpret_cast<const uint4*>(a + off);
        rA1 = *reinterpret_cast<const uint4*>(a + off + 8);
    };
    auto loadB = [&](int kb) {
        size_t off = (size_t)bgrow * KTOT + kb + skc;
        rB0 = *reinterpret_cast<const uint4*>(BT + off);
        rB1 = *reinterpret_cast<const uint4*>(BT + off + 8);
    };
    auto stageWrite = [&](_Float16* sA, _Float16* sB) {
        *reinterpret_cast<uint4*>(&sA[sw1]) = rA0;
        *reinterpret_cast<uint4*>(&sA[sw2]) = rA1;
        *reinterpret_cast<uint4*>(&sB[sw1]) = rB0;
        *reinterpret_cast<uint4*>(&sB[sw2]) = rB1;
    };

    // prologue: stage 0 filled, tile 1 loads in flight
    loadA(0); loadB(0);
    stageWrite(s0, s0 + 64 * LSTR);
    if (NIT > 1) { loadA(128); loadB(128); }
    __syncthreads();

    f32x4 acc[4] = {};
    const int arow = wpair * 16 + (lane & 15);
    const int abase = arow * LSTR;
    const int aswz = (arow & 7) << 3;
    const int kfrag = ksub * 64 + ((lane >> 4) << 3);

    for (int i = 0; i < NIT; ++i) {
        _Float16* cA = s0 + (i & 1) * STG;
        _Float16* cB = cA + 64 * LSTR;
        if (i + 1 < NIT) {
            _Float16* nA = s0 + ((i + 1) & 1) * STG;
            stageWrite(nA, nA + 64 * LSTR);        // waits on tile i+1 loads
        }
        if (i + 2 < NIT) { loadA((i + 2) * 128); loadB((i + 2) * 128); }
#pragma unroll
        for (int kk = 0; kk < 2; ++kk) {
            int ko = kfrag + kk * 32;
            f16x8 a = *reinterpret_cast<const f16x8*>(&cA[abase + (ko ^ aswz)]);
#pragma unroll
            for (int g = 0; g < 4; ++g) {
                int br = g * 16 + (lane & 15);
                f16x8 b = *reinterpret_cast<const f16x8*>(&cB[br * LSTR + (ko ^ ((br & 7) << 3))]);
                acc[g] = __builtin_amdgcn_mfma_f32_16x16x32_f16(b, a, acc[g], 0, 0, 0);
            }
        }
        __syncthreads();                  // one barrier per iter
    }

    // epilogue (staging reads done; szred may alias)
    if (ksub == 1) {
        float* zr = &szred[(wpair * 64 + lane) * 21];
#pragma unroll
        for (int g = 0; g < 4; ++g)
#pragma unroll
            for (int r = 0; r < 4; ++r)
                zr[g * 4 + r] = acc[g][r];
    }
    __syncthreads();
    if (ksub == 0) {
        const int row  = m0 + wpair * 16 + (lane & 15);
        const int colb = j0 + ((lane >> 4) << 2);
        const float* zr = &szred[(wpair * 64 + lane) * 21];
        f32x4 bi4 = *reinterpret_cast<const f32x4*>(&bias[colb]);
        f32x4 bf4 = *reinterpret_cast<const f32x4*>(&bias[512 + colb]);
        f32x4 bg4 = *reinterpret_cast<const f32x4*>(&bias[1024 + colb]);
        f32x4 bo4 = *reinterpret_cast<const f32x4*>(&bias[1536 + colb]);
        f32x4 c4 = *reinterpret_cast<f32x4*>(&cst[row * H_ + colb]);
        union { _Float16 h[4]; u64 u; } hh;
        f32x4 h4;
#pragma unroll
        for (int r = 0; r < 4; ++r) {
            float zi = acc[0][r] + zr[0 + r] + bi4[r];
            float zf = acc[1][r] + zr[4 + r] + bf4[r];
            float zg = acc[2][r] + zr[8 + r] + bg4[r];
            float zo = acc[3][r] + zr[12 + r] + bo4[r];
            float gi = sigm(zi), gf = sigm(zf), gg = tanh_(zg), go = sigm(zo);
            float c = gf * c4[r] + gi * gg;
            c4[r] = c;
            float h = go * tanh_(c);
            h4[r] = h;
            hh.h[r] = (_Float16)h;
        }
        *reinterpret_cast<f32x4*>(&cst[row * H_ + colb]) = c4;
        *reinterpret_cast<u64*>(&hout[row * H_ + colb]) = hh.u;
        if (hout_f32) *reinterpret_cast<f32x4*>(&hout_f32[row * H_ + colb]) = h4;
    }
}

// ---------------- pred: one 16x16 tile/WG, 8-wave K-split, direct frag loads ----------------
// Grid 256 WGs (32 b-row tiles x 8 d-col tiles), 512 threads.  (r9 verbatim)
__global__ __launch_bounds__(512) void k_pred(
    const _Float16* __restrict__ h1prev, // [512][512]
    const _Float16* __restrict__ WT,     // [128][512]
    const float* __restrict__ bout,
    const float* __restrict__ x,         // [512][256][128]
    int t,
    _Float16* __restrict__ cur,          // [512][128]
    float* __restrict__ outPred)         // [B*(T-1)][128] region of d_out
{
    __shared__ float sred[512 * 5];

    const int tid = threadIdx.x;
    const int wave = tid >> 6, l = tid & 63;
    const int pr = blockIdx.x >> 3;       // b-row tile 0..31
    const int pc = blockIdx.x & 7;        // d-col tile 0..7
    const int arow = (pr * 16 + (l & 15)) * 512;
    const int brow = (pc * 16 + (l & 15)) * 512;
    const int kof = (l >> 4) << 3;

    f32x4 acc = {};
#pragma unroll
    for (int kk = 0; kk < 2; ++kk) {
        int k = wave * 64 + kk * 32 + kof;
        f16x8 a = *reinterpret_cast<const f16x8*>(h1prev + arow + k);
        f16x8 b = *reinterpret_cast<const f16x8*>(WT + brow + k);
        // swapped: lane holds b=pr*16+(l&15), d=pc*16+(l>>4)*4+r
        acc = __builtin_amdgcn_mfma_f32_16x16x32_f16(b, a, acc, 0, 0, 0);
    }
    {
        float* sr = &sred[(wave * 64 + l) * 5];
#pragma unroll
        for (int r = 0; r < 4; ++r) sr[r] = acc[r];
    }
    __syncthreads();
    if (wave == 0) {
#pragma unroll
        for (int w = 1; w < 8; ++w) {
            const float* sr = &sred[(w * 64 + l) * 5];
#pragma unroll
            for (int r = 0; r < 4; ++r) acc[r] += sr[r];
        }
        const int b = pr * 16 + (l & 15);
        const int colb = pc * 16 + ((l >> 4) << 2);
        f32x4 bo4 = *reinterpret_cast<const f32x4*>(&bout[colb]);
        f32x4 xv4 = *reinterpret_cast<const f32x4*>(&x[((size_t)b * T_ + t) * D_ + colb]);
        f32x4 p4;
        union { _Float16 h[4]; u64 u; } ch;
#pragma unroll
        for (int r = 0; r < 4; ++r) {
            float pred = acc[r] + bo4[r];
            p4[r] = pred;
            float cv = (xv4[r] == 128.0f) ? pred : xv4[r];
            ch.h[r] = (_Float16)cv;
        }
        *reinterpret_cast<f32x4*>(&outPred[((size_t)b * (T_ - 1) + (t - 1)) * D_ + colb]) = p4;
        *reinterpret_cast<u64*>(&cur[b * D_ + colb]) = ch.u;
    }
}

extern "C" void kernel_launch(void* const* d_in, const int* in_sizes, int n_in,
                              void* d_out, int out_size, void* d_ws, size_t ws_size,
                              hipStream_t stream)
{
    const float* x  = (const float*)d_in[0];
    const float* k0 = (const float*)d_in[1];
    const float* r0 = (const float*)d_in[2];
    const float* b0 = (const float*)d_in[3];
    const float* k1 = (const float*)d_in[4];
    const float* r1 = (const float*)d_in[5];
    const float* b1 = (const float*)d_in[6];
    const float* W  = (const float*)d_in[7];
    const float* bo = (const float*)d_in[8];
    float* out = (float*)d_out;

    char* ws = (char*)d_ws;
    size_t off = 0;
    auto alloc = [&](size_t bytes) { void* p = ws + off; off += (bytes + 255) & ~255ull; return p; };
    _Float16* wB0T = (_Float16*)alloc((size_t)2048 * 640 * 2);
    _Float16* wB1T = (_Float16*)alloc((size_t)2048 * 1024 * 2);
    _Float16* wWT  = (_Float16*)alloc((size_t)128 * 512 * 2);
    _Float16* cur  = (_Float16*)alloc((size_t)B_ * D_ * 2);
    _Float16* h0[2] = { (_Float16*)alloc((size_t)B_ * H_ * 2), (_Float16*)alloc((size_t)B_ * H_ * 2) };
    _Float16* h1[2] = { (_Float16*)alloc((size_t)B_ * H_ * 2), (_Float16*)alloc((size_t)B_ * H_ * 2) };
    float* c0 = (float*)alloc((size_t)B_ * H_ * 4);
    float* c1 = (float*)alloc((size_t)B_ * H_ * 4);

    k_convert<<<2048, 256, 0, stream>>>(k0, r0, k1, r1, W, wB0T, wB1T, wWT);
    k_init<<<1024, 256, 0, stream>>>(x, cur, h0[0], h0[1], h1[0], h1[1], c0, c1);

    float* lastcell = out + (size_t)B_ * (T_ - 1) * D_;

    for (int t = 0; t < T_; ++t) {
        int cu = t & 1, pv = cu ^ 1;
        if (t > 0)
            k_pred<<<256, 512, 0, stream>>>(h1[pv], wWT, bo, x, t, cur, out);
        k_layer<640, 128><<<dim3(32, 8), 512, 0, stream>>>(
            cur, D_, h0[pv], H_, wB0T, b0, c0, h0[cu], nullptr);
        k_layer<1024, 512><<<dim3(32, 8), 512, 0, stream>>>(
            h0[cu], H_, h1[pv], H_, wB1T, b1, c1, h1[cu],
            (t == T_ - 1) ? lastcell : nullptr);
    }
}

// Round 14
// 5121.081 us; speedup vs baseline: 2.1277x; 1.0125x over previous
//
#include <hip/hip_runtime.h>

#define B_ 512
#define T_ 256
#define D_ 128
#define H_ 512

typedef _Float16 f16x8 __attribute__((ext_vector_type(8)));
typedef float f32x4 __attribute__((ext_vector_type(4)));
typedef unsigned long long u64;

__device__ __forceinline__ float sigm(float x) { return 1.f / (1.f + __expf(-x)); }
__device__ __forceinline__ float tanh_(float x) { return 2.f / (1.f + __expf(-2.f * x)) - 1.f; }

// ---------------- weight convert: fp32 -> fp16, transposed to [N][K] ----------------
__global__ void k_convert(const float* __restrict__ k0, const float* __restrict__ r0,
                          const float* __restrict__ k1, const float* __restrict__ r1,
                          const float* __restrict__ W,
                          _Float16* __restrict__ wB0T,  // [2048][640]
                          _Float16* __restrict__ wB1T,  // [2048][1024]
                          _Float16* __restrict__ wWT)   // [128][512]
{
    int tid = blockIdx.x * blockDim.x + threadIdx.x;
    int nth = gridDim.x * blockDim.x;
    for (int idx = tid; idx < 640 * 2048; idx += nth) {
        int k = idx >> 11, n = idx & 2047;
        float v = (k < 128) ? k0[k * 2048 + n] : r0[(k - 128) * 2048 + n];
        wB0T[n * 640 + k] = (_Float16)v;
    }
    for (int idx = tid; idx < 1024 * 2048; idx += nth) {
        int k = idx >> 11, n = idx & 2047;
        float v = (k < 512) ? k1[k * 2048 + n] : r1[(k - 512) * 2048 + n];
        wB1T[n * 1024 + k] = (_Float16)v;
    }
    for (int idx = tid; idx < 512 * 128; idx += nth) {
        int k = idx >> 7, n = idx & 127;
        wWT[n * 512 + k] = (_Float16)W[k * 128 + n];
    }
}

// ---------------- init: cur = x[:,0,:] fp16, zero h/c state ----------------
__global__ void k_init(const float* __restrict__ x, _Float16* __restrict__ cur,
                       _Float16* __restrict__ h0a, _Float16* __restrict__ h0b,
                       _Float16* __restrict__ h1a, _Float16* __restrict__ h1b,
                       float* __restrict__ c0, float* __restrict__ c1)
{
    int tid = blockIdx.x * blockDim.x + threadIdx.x;
    int nth = gridDim.x * blockDim.x;
    for (int idx = tid; idx < B_ * D_; idx += nth) {
        int b = idx >> 7, d = idx & 127;
        cur[idx] = (_Float16)x[b * (T_ * D_) + d];   // t=0: 128.0 exact in fp16
    }
    for (int idx = tid; idx < B_ * H_; idx += nth) {
        h0a[idx] = (_Float16)0.f; h0b[idx] = (_Float16)0.f;
        h1a[idx] = (_Float16)0.f; h1b[idx] = (_Float16)0.f;
        c0[idx] = 0.f; c1[idx] = 0.f;
    }
}

// ---------------- one LSTM layer step, fp16 GEMM, BK=128, swizzled LDS ----------------
// z^T fragments via swapped-operand MFMA: lane owns row m0+wpair*16+(lane&15),
// 4 consecutive cols j0+(lane>>4)*4..+3. A=[A1|A2] K-segments; BT [2048][KTOT].
// 8 waves: wpair=wave>>1 (16-row group), ksub=wave&1 (K-half of the 128 tile).
template <int KTOT, int K1>
__global__ __launch_bounds__(512) void k_layer(
    const _Float16* __restrict__ A1, int lda1,
    const _Float16* __restrict__ A2, int lda2,
    const _Float16* __restrict__ BT,
    const float* __restrict__ bias,       // [2048] gate order i,f,g,o
    float* __restrict__ cst,              // [512][512] fp32 rmw
    _Float16* __restrict__ hout,
    float* __restrict__ hout_f32)         // optional fp32 copy (last_cell)
{
    constexpr int LSTR = 144;
    __shared__ __align__(16) char smem[2 * 64 * LSTR * 2];   // 36864 B
    _Float16* sA = (_Float16*)smem;
    _Float16* sB = sA + 64 * LSTR;
    float* szred = (float*)smem;          // aliased after main loop (barrier-separated)

    const int j0 = blockIdx.x * 16;
    const int m0 = blockIdx.y * 64;
    const int tid = threadIdx.x;
    const int lane = tid & 63;
    const int wave = tid >> 6;
    const int wpair = wave >> 1;
    const int ksub = wave & 1;

    // staging: thread -> (row, 16-elem k chunk)
    const int srow = tid >> 3;
    const int skc = (tid & 7) << 4;       // 0,16,...,112
    const int swz = (srow & 7) << 3;
    const int sw1 = srow * LSTR + (skc ^ swz);
    const int sw2 = srow * LSTR + ((skc + 8) ^ swz);
    const int bgrow = (srow >> 4) * 512 + j0 + (srow & 15);

    uint4 rA0, rA1, rB0, rB1;
    auto loadA = [&](int kb) {
        int k = kb + skc;
        const _Float16* a; size_t off;
        if (k < K1) { a = A1; off = (size_t)(m0 + srow) * lda1 + k; }
        else        { a = A2; off = (size_t)(m0 + srow) * lda2 + (k - K1); }
        rA0 = *reinterpret_cast<const uint4*>(a + off);
        rA1 = *reinterpret_cast<const uint4*>(a + off + 8);
    };
    auto loadB = [&](int kb) {
        size_t off = (size_t)bgrow * KTOT + kb + skc;
        rB0 = *reinterpret_cast<const uint4*>(BT + off);
        rB1 = *reinterpret_cast<const uint4*>(BT + off + 8);
    };

    loadA(0); loadB(0);

    f32x4 acc[4] = {};
    const int arow = wpair * 16 + (lane & 15);
    const int abase = arow * LSTR;
    const int aswz = (arow & 7) << 3;
    const int kfrag = ksub * 64 + ((lane >> 4) << 3);

    for (int kb = 0; kb < KTOT; kb += 128) {
        __syncthreads();
        *reinterpret_cast<uint4*>(&sA[sw1]) = rA0;
        *reinterpret_cast<uint4*>(&sA[sw2]) = rA1;
        *reinterpret_cast<uint4*>(&sB[sw1]) = rB0;
        *reinterpret_cast<uint4*>(&sB[sw2]) = rB1;
        if (kb + 128 < KTOT) { loadA(kb + 128); loadB(kb + 128); }
        __syncthreads();
#pragma unroll
        for (int kk = 0; kk < 2; ++kk) {
            int ko = kfrag + kk * 32;
            f16x8 a = *reinterpret_cast<const f16x8*>(&sA[abase + (ko ^ aswz)]);
#pragma unroll
            for (int g = 0; g < 4; ++g) {
                int br = g * 16 + (lane & 15);
                f16x8 b = *reinterpret_cast<const f16x8*>(&sB[br * LSTR + (ko ^ ((br & 7) << 3))]);
                acc[g] = __builtin_amdgcn_mfma_f32_16x16x32_f16(b, a, acc[g], 0, 0, 0);
            }
        }
    }

    __syncthreads();                      // staging reads done; szred may alias
    if (ksub == 1) {
        float* zr = &szred[(wpair * 64 + lane) * 21];
#pragma unroll
        for (int g = 0; g < 4; ++g)
#pragma unroll
            for (int r = 0; r < 4; ++r)
                zr[g * 4 + r] = acc[g][r];
    }
    __syncthreads();
    if (ksub == 0) {
        const int row  = m0 + wpair * 16 + (lane & 15);
        const int colb = j0 + ((lane >> 4) << 2);
        const float* zr = &szred[(wpair * 64 + lane) * 21];
        f32x4 bi4 = *reinterpret_cast<const f32x4*>(&bias[colb]);
        f32x4 bf4 = *reinterpret_cast<const f32x4*>(&bias[512 + colb]);
        f32x4 bg4 = *reinterpret_cast<const f32x4*>(&bias[1024 + colb]);
        f32x4 bo4 = *reinterpret_cast<const f32x4*>(&bias[1536 + colb]);
        f32x4 c4 = *reinterpret_cast<f32x4*>(&cst[row * H_ + colb]);
        union { _Float16 h[4]; u64 u; } hh;
        f32x4 h4;
#pragma unroll
        for (int r = 0; r < 4; ++r) {
            float zi = acc[0][r] + zr[0 + r] + bi4[r];
            float zf = acc[1][r] + zr[4 + r] + bf4[r];
            float zg = acc[2][r] + zr[8 + r] + bg4[r];
            float zo = acc[3][r] + zr[12 + r] + bo4[r];
            float gi = sigm(zi), gf = sigm(zf), gg = tanh_(zg), go = sigm(zo);
            float c = gf * c4[r] + gi * gg;
            c4[r] = c;
            float h = go * tanh_(c);
            h4[r] = h;
            hh.h[r] = (_Float16)h;
        }
        *reinterpret_cast<f32x4*>(&cst[row * H_ + colb]) = c4;
        *reinterpret_cast<u64*>(&hout[row * H_ + colb]) = hh.u;
        if (hout_f32) *reinterpret_cast<f32x4*>(&hout_f32[row * H_ + colb]) = h4;
    }
}

// ---------------- pred: one 16x16 tile/WG, 8-wave K-split, direct frag loads ----------------
// Grid 256 WGs (32 b-row tiles x 8 d-col tiles), 512 threads.
__global__ __launch_bounds__(512) void k_pred(
    const _Float16* __restrict__ h1prev, // [512][512]
    const _Float16* __restrict__ WT,     // [128][512]
    const float* __restrict__ bout,
    const float* __restrict__ x,         // [512][256][128]
    int t,
    _Float16* __restrict__ cur,          // [512][128]
    float* __restrict__ outPred)         // [B*(T-1)][128] region of d_out
{
    __shared__ float sred[512 * 5];

    const int tid = threadIdx.x;
    const int wave = tid >> 6, l = tid & 63;
    const int pr = blockIdx.x >> 3;       // b-row tile 0..31
    const int pc = blockIdx.x & 7;        // d-col tile 0..7
    const int arow = (pr * 16 + (l & 15)) * 512;
    const int brow = (pc * 16 + (l & 15)) * 512;
    const int kof = (l >> 4) << 3;

    f32x4 acc = {};
#pragma unroll
    for (int kk = 0; kk < 2; ++kk) {
        int k = wave * 64 + kk * 32 + kof;
        f16x8 a = *reinterpret_cast<const f16x8*>(h1prev + arow + k);
        f16x8 b = *reinterpret_cast<const f16x8*>(WT + brow + k);
        // swapped: lane holds b=pr*16+(l&15), d=pc*16+(l>>4)*4+r
        acc = __builtin_amdgcn_mfma_f32_16x16x32_f16(b, a, acc, 0, 0, 0);
    }
    {
        float* sr = &sred[(wave * 64 + l) * 5];
#pragma unroll
        for (int r = 0; r < 4; ++r) sr[r] = acc[r];
    }
    __syncthreads();
    if (wave == 0) {
#pragma unroll
        for (int w = 1; w < 8; ++w) {
            const float* sr = &sred[(w * 64 + l) * 5];
#pragma unroll
            for (int r = 0; r < 4; ++r) acc[r] += sr[r];
        }
        const int b = pr * 16 + (l & 15);
        const int colb = pc * 16 + ((l >> 4) << 2);
        f32x4 bo4 = *reinterpret_cast<const f32x4*>(&bout[colb]);
        f32x4 xv4 = *reinterpret_cast<const f32x4*>(&x[((size_t)b * T_ + t) * D_ + colb]);
        f32x4 p4;
        union { _Float16 h[4]; u64 u; } ch;
#pragma unroll
        for (int r = 0; r < 4; ++r) {
            float pred = acc[r] + bo4[r];
            p4[r] = pred;
            float cv = (xv4[r] == 128.0f) ? pred : xv4[r];
            ch.h[r] = (_Float16)cv;
        }
        *reinterpret_cast<f32x4*>(&outPred[((size_t)b * (T_ - 1) + (t - 1)) * D_ + colb]) = p4;
        *reinterpret_cast<u64*>(&cur[b * D_ + colb]) = ch.u;
    }
}

extern "C" void kernel_launch(void* const* d_in, const int* in_sizes, int n_in,
                              void* d_out, int out_size, void* d_ws, size_t ws_size,
                              hipStream_t stream)
{
    const float* x  = (const float*)d_in[0];
    const float* k0 = (const float*)d_in[1];
    const float* r0 = (const float*)d_in[2];
    const float* b0 = (const float*)d_in[3];
    const float* k1 = (const float*)d_in[4];
    const float* r1 = (const float*)d_in[5];
    const float* b1 = (const float*)d_in[6];
    const float* W  = (const float*)d_in[7];
    const float* bo = (const float*)d_in[8];
    float* out = (float*)d_out;

    char* ws = (char*)d_ws;
    size_t off = 0;
    auto alloc = [&](size_t bytes) { void* p = ws + off; off += (bytes + 255) & ~255ull; return p; };
    _Float16* wB0T = (_Float16*)alloc((size_t)2048 * 640 * 2);
    _Float16* wB1T = (_Float16*)alloc((size_t)2048 * 1024 * 2);
    _Float16* wWT  = (_Float16*)alloc((size_t)128 * 512 * 2);
    _Float16* cur  = (_Float16*)alloc((size_t)B_ * D_ * 2);
    _Float16* h0[2] = { (_Float16*)alloc((size_t)B_ * H_ * 2), (_Float16*)alloc((size_t)B_ * H_ * 2) };
    _Float16* h1[2] = { (_Float16*)alloc((size_t)B_ * H_ * 2), (_Float16*)alloc((size_t)B_ * H_ * 2) };
    float* c0 = (float*)alloc((size_t)B_ * H_ * 4);
    float* c1 = (float*)alloc((size_t)B_ * H_ * 4);

    k_convert<<<2048, 256, 0, stream>>>(k0, r0, k1, r1, W, wB0T, wB1T, wWT);
    k_init<<<1024, 256, 0, stream>>>(x, cur, h0[0], h0[1], h1[0], h1[1], c0, c1);

    float* lastcell = out + (size_t)B_ * (T_ - 1) * D_;

    for (int t = 0; t < T_; ++t) {
        int cu = t & 1, pv = cu ^ 1;
        if (t > 0)
            k_pred<<<256, 512, 0, stream>>>(h1[pv], wWT, bo, x, t, cur, out);
        k_layer<640, 128><<<dim3(32, 8), 512, 0, stream>>>(
            cur, D_, h0[pv], H_, wB0T, b0, c0, h0[cu], nullptr);
        k_layer<1024, 512><<<dim3(32, 8), 512, 0, stream>>>(
            h0[cu], H_, h1[pv], H_, wB1T, b1, c1, h1[cu],
            (t == T_ - 1) ? lastcell : nullptr);
    }
}